// Round 3
// baseline (409.421 us; speedup 1.0000x reference)
//
#include <hip/hip_runtime.h>
#include <math.h>

// Quadrotor dynamics, B=2^20 independent 32-float AoS rows.
// R2 was latency-bound (2.4 TB/s, VALU 22%, occ 33%): 8KB/wave in flight,
// block barriers gang-coupled waves. R3: per-wave LDS tiles (NO __syncthreads,
// wave-local lgkmcnt fence), UNROLL=2 with all 16 dwordx4 loads issued
// up-front (2x MLP), stride-32 tile + rotation swizzle (conflict-free, no pad,
// 32KB/block -> 5 blocks/CU), accumulate-RK4 to hold VGPR ~<=128.

#define INV_MASSF  (1.0f / 1.5f)
#define GRAVF      9.81f
#define KDF        0.1f
#define KHF        0.01f
#define JXF        0.0211f
#define JYF        0.0219f
#define JZF        0.0366f
#define JIXF       (1.0f / 0.0211f)
#define JIYF       (1.0f / 0.0219f)
#define JIZF       (1.0f / 0.0366f)
#define PI_2F      1.57079632679489661923f

// wave-local LDS fence: LDS pipe is in-order per wave; this orders compiler
// emission and drains lgkm before dependent cross-lane reads.
#define FENCE_LDS() __asm__ volatile("s_waitcnt lgkmcnt(0)" ::: "memory")

__device__ __forceinline__ void rb_deriv(const float x[13], const float fm[6], float k[13]) {
    k[0] = x[3]; k[1] = x[4]; k[2] = x[5];
    k[3] = fm[0] * INV_MASSF;
    k[4] = fm[1] * INV_MASSF;
    k[5] = fm[2] * INV_MASSF + GRAVF;
    const float ew = x[6], ex = x[7], ey = x[8], ez = x[9];
    const float p = x[10], q = x[11], r = x[12];
    k[6] = 0.5f * (-ex * p - ey * q - ez * r);
    k[7] = 0.5f * ( ew * p + ey * r - ez * q);
    k[8] = 0.5f * ( ew * q - ex * r + ez * p);
    k[9] = 0.5f * ( ew * r + ex * q - ey * p);
    const float Jwx = JXF * p, Jwy = JYF * q, Jwz = JZF * r;
    k[10] = (fm[3] - (q * Jwz - r * Jwy)) * JIXF;
    k[11] = (fm[4] - (r * Jwx - p * Jwz)) * JIYF;
    k[12] = (fm[5] - (p * Jwy - q * Jwx)) * JIZF;
}

__device__ __forceinline__ void qd_compute(const float s[32], float4 dl,
                                           const float g[16], float dt,
                                           float o[32]) {
    float d0 = fminf(fmaxf(dl.x, 0.0f), 1000.0f);
    float d1 = fminf(fmaxf(dl.y, 0.0f), 1000.0f);
    float d2 = fminf(fmaxf(dl.z, 0.0f), 1000.0f);
    float d3 = fminf(fmaxf(dl.w, 0.0f), 1000.0f);
    d0 *= d0; d1 *= d1; d2 *= d2; d3 *= d3;
    const float T  = g[0]  * d0 + g[1]  * d1 + g[2]  * d2 + g[3]  * d3;
    const float Mx = g[4]  * d0 + g[5]  * d1 + g[6]  * d2 + g[7]  * d3;
    const float My = g[8]  * d0 + g[9]  * d1 + g[10] * d2 + g[11] * d3;
    const float Mz = g[12] * d0 + g[13] * d1 + g[14] * d2 + g[15] * d3;

    const float ew = s[9], ex = s[10], ey = s[11], ez = s[12];
    const float r00 = ew*ew + ex*ex - ey*ey - ez*ez;
    const float r01 = 2.0f * (ex*ey - ew*ez);
    const float r02 = 2.0f * (ex*ez + ew*ey);
    const float r10 = 2.0f * (ex*ey + ew*ez);
    const float r11 = ew*ew - ex*ex + ey*ey - ez*ez;
    const float r12 = 2.0f * (ey*ez - ew*ex);
    const float r20 = 2.0f * (ex*ez - ew*ey);
    const float r21 = 2.0f * (ey*ez + ew*ex);
    const float r22 = ew*ew - ex*ex - ey*ey + ez*ez;

    const float wx = s[28], wy = s[29], wz = s[30];
    const float vwb0 = r00 * wx + r10 * wy + r20 * wz;
    const float vwb1 = r01 * wx + r11 * wy + r21 * wz;
    const float vwb2 = r02 * wx + r12 * wy + r22 * wz;

    const float u_r = s[16] - vwb0;
    const float v_r = s[17] - vwb1;
    const float w_r = s[18] - vwb2;
    const float Va = sqrtf(u_r * u_r + v_r * v_r + w_r * w_r);
    const float alpha = (u_r == 0.0f) ? PI_2F : atan2f(w_r, u_r);
    const float beta = (Va == 0.0f)
        ? 0.0f
        : asinf(fminf(fmaxf(v_r / Va, -1.0f), 1.0f));

    const float fx = -KDF * u_r;
    const float fy = -KDF * v_r;
    const float fz = -T - KDF * w_r + KHF * (u_r * u_r + v_r * v_r);
    float fm[6];
    fm[0] = r00 * fx + r01 * fy + r02 * fz;
    fm[1] = r10 * fx + r11 * fy + r12 * fz;
    fm[2] = r20 * fx + r21 * fy + r22 * fz;
    fm[3] = Mx; fm[4] = My; fm[5] = Mz;

    // ---- RK4, accumulate form (k1..k4 never co-live -> lower VGPR) ----
    float x0[13];
    x0[0] = s[3];  x0[1] = s[4];  x0[2] = s[5];
    x0[3] = s[13]; x0[4] = s[14]; x0[5] = s[15];
    x0[6] = s[9];  x0[7] = s[10]; x0[8] = s[11]; x0[9] = s[12];
    x0[10] = s[19]; x0[11] = s[20]; x0[12] = s[21];

    const float hdt = 0.5f * dt;
    const float dt6 = dt / 6.0f;
    float k[13], acc[13], xt[13], xn[13];
    rb_deriv(x0, fm, k);                       // k1
    #pragma unroll
    for (int i = 0; i < 13; ++i) { acc[i] = k[i]; xt[i] = x0[i] + hdt * k[i]; }
    rb_deriv(xt, fm, k);                       // k2
    #pragma unroll
    for (int i = 0; i < 13; ++i) { acc[i] += 2.0f * k[i]; xt[i] = x0[i] + hdt * k[i]; }
    rb_deriv(xt, fm, k);                       // k3
    #pragma unroll
    for (int i = 0; i < 13; ++i) { acc[i] += 2.0f * k[i]; xt[i] = x0[i] + dt * k[i]; }
    rb_deriv(xt, fm, k);                       // k4
    #pragma unroll
    for (int i = 0; i < 13; ++i) xn[i] = x0[i] + dt6 * (acc[i] + k[i]);

    float qw = xn[6], qx = xn[7], qy = xn[8], qz = xn[9];
    const float qn = sqrtf(qw * qw + qx * qx + qy * qy + qz * qz);
    qw /= qn; qx /= qn; qy /= qn; qz /= qn;

    const float phi = atan2f(2.0f * (qw * qx + qy * qz),
                             qw * qw + qz * qz - qx * qx - qy * qy);
    const float theta = asinf(fminf(fmaxf(2.0f * (qw * qy - qx * qz), -1.0f), 1.0f));
    const float psi = atan2f(2.0f * (qw * qz + qx * qy),
                             qw * qw + qx * qx - qy * qy - qz * qz);

    const float p0 = r00 * s[16] + r01 * s[17] + r02 * s[18];
    const float p1 = r10 * s[16] + r11 * s[17] + r12 * s[18];
    const float p2 = r20 * s[16] + r21 * s[17] + r22 * s[18];
    const float Vg = sqrtf(p0 * p0 + p1 * p1 + p2 * p2);
    const float vg_safe = (Vg == 0.0f) ? 1.0f : Vg;
    const float gamma = asinf(fminf(fmaxf(p2 / vg_safe, -1.0f), 1.0f));
    const float chi = atan2f(p1, p0);

    o[0] = s[0]; o[1] = s[1]; o[2] = s[2];
    o[3] = xn[0]; o[4] = xn[1]; o[5] = xn[2];
    o[6] = phi; o[7] = theta; o[8] = psi;
    o[9] = qw; o[10] = qx; o[11] = qy; o[12] = qz;
    o[13] = xn[3]; o[14] = xn[4]; o[15] = xn[5];
    o[16] = s[16]; o[17] = s[17]; o[18] = s[18];
    o[19] = xn[10]; o[20] = xn[11]; o[21] = xn[12];
    o[22] = Va; o[23] = Vg;
    o[24] = alpha; o[25] = beta;
    o[26] = gamma; o[27] = chi;
    o[28] = s[28]; o[29] = s[29]; o[30] = s[30]; o[31] = s[31];
}

__global__ __launch_bounds__(256) void qd_dynamics_kernel(
    const float* __restrict__ state,
    const float* __restrict__ delta,
    const float* __restrict__ G1,
    const float* __restrict__ dtp,
    float* __restrict__ out,
    int B)
{
    // per-wave 64x32 tiles, stride 32 (no pad; rotation swizzle kills conflicts)
    __shared__ float lds[4][64 * 32];      // 32 KB

    const int tid  = threadIdx.x;
    const int lane = tid & 63;
    const int wave = tid >> 6;
    float* tile = &lds[wave][0];

    const int rowA = blockIdx.x * 512 + wave * 128;  // this wave's chunk A
    const int rowB = rowA + 64;                      // chunk B

    const float dt = dtp[0];
    float g[16];
    {
        const float4* gp = (const float4*)G1;
        #pragma unroll
        for (int i = 0; i < 4; ++i) ((float4*)g)[i] = gp[i];
    }

    float sA[32], sB[32], o[32];

    if (rowB + 64 <= B) {
        // ---- issue ALL global loads up front (16 dwordx4 + 2 delta / lane) ----
        const float4* gA4 = (const float4*)(state + (size_t)rowA * 32);
        const float4* gB4 = (const float4*)(state + (size_t)rowB * 32);
        float4 gA[8], gB[8];
        #pragma unroll
        for (int i = 0; i < 8; ++i) gA[i] = gA4[i * 64 + lane];
        #pragma unroll
        for (int i = 0; i < 8; ++i) gB[i] = gB4[i * 64 + lane];
        const float4 dlA = ((const float4*)delta)[rowA + lane];
        const float4 dlB = ((const float4*)delta)[rowB + lane];

        // ---- stage A: plain write, rotated read (conflict-free both ways) ----
        #pragma unroll
        for (int i = 0; i < 8; ++i) {
            const int f4 = i * 64 + lane;
            *(float4*)&tile[(f4 >> 3) * 32 + (f4 & 7) * 4] = gA[i];
        }
        FENCE_LDS();
        #pragma unroll
        for (int i = 0; i < 8; ++i) {
            const int c = (i + lane) & 7;
            ((float4*)sA)[c] = *(const float4*)&tile[lane * 32 + c * 4];
        }
        FENCE_LDS();
        // ---- stage B ----
        #pragma unroll
        for (int i = 0; i < 8; ++i) {
            const int f4 = i * 64 + lane;
            *(float4*)&tile[(f4 >> 3) * 32 + (f4 & 7) * 4] = gB[i];
        }
        FENCE_LDS();
        #pragma unroll
        for (int i = 0; i < 8; ++i) {
            const int c = (i + lane) & 7;
            ((float4*)sB)[c] = *(const float4*)&tile[lane * 32 + c * 4];
        }

        // ---- compute + emit A ----
        qd_compute(sA, dlA, g, dt, o);
        FENCE_LDS();                       // sB reads drained before overwrite
        #pragma unroll
        for (int j = 0; j < 8; ++j) {
            const int c = (j + lane) & 7;
            *(float4*)&tile[lane * 32 + c * 4] = ((const float4*)o)[c];
        }
        FENCE_LDS();
        {
            float4* oA4 = (float4*)(out + (size_t)rowA * 32);
            #pragma unroll
            for (int i = 0; i < 8; ++i) {
                const int f4 = i * 64 + lane;
                oA4[f4] = *(const float4*)&tile[(f4 >> 3) * 32 + (f4 & 7) * 4];
            }
        }
        FENCE_LDS();                       // stage-out reads drained

        // ---- compute + emit B ----
        qd_compute(sB, dlB, g, dt, o);
        #pragma unroll
        for (int j = 0; j < 8; ++j) {
            const int c = (j + lane) & 7;
            *(float4*)&tile[lane * 32 + c * 4] = ((const float4*)o)[c];
        }
        FENCE_LDS();
        {
            float4* oB4 = (float4*)(out + (size_t)rowB * 32);
            #pragma unroll
            for (int i = 0; i < 8; ++i) {
                const int f4 = i * 64 + lane;
                oB4[f4] = *(const float4*)&tile[(f4 >> 3) * 32 + (f4 & 7) * 4];
            }
        }
    } else {
        // tail (never taken for B=2^20; correctness fallback, direct AoS I/O)
        #pragma unroll
        for (int u = 0; u < 2; ++u) {
            const int b = rowA + u * 64 + lane;
            if (b < B) {
                const float4* sp = (const float4*)(state + (size_t)b * 32);
                #pragma unroll
                for (int i = 0; i < 8; ++i) ((float4*)sA)[i] = sp[i];
                const float4 dl = ((const float4*)delta)[b];
                qd_compute(sA, dl, g, dt, o);
                float4* op = (float4*)(out + (size_t)b * 32);
                #pragma unroll
                for (int i = 0; i < 8; ++i) op[i] = ((const float4*)o)[i];
            }
        }
    }
}

extern "C" void kernel_launch(void* const* d_in, const int* in_sizes, int n_in,
                              void* d_out, int out_size, void* d_ws, size_t ws_size,
                              hipStream_t stream) {
    const float* state = (const float*)d_in[0];
    const float* delta = (const float*)d_in[1];
    const float* G1    = (const float*)d_in[2];
    const float* dtp   = (const float*)d_in[3];
    float* out = (float*)d_out;
    const int B = in_sizes[0] / 32;
    const int grid = (B + 511) / 512;
    hipLaunchKernelGGL(qd_dynamics_kernel, dim3(grid), dim3(256), 0, stream,
                       state, delta, G1, dtp, out, B);
}